// Round 11
// baseline (172.575 us; speedup 1.0000x reference)
//
#include <hip/hip_runtime.h>

// ONN conv2d: B=16, Cin=128, H=W=32, Cout=256, k=3 (pad=1, stride=1)
// N=16384 positions, D=1152=18*64 chunks of VEC=64, M=256.
// out[n,m] = sum_r sign01( dot_c( x[n,64r+c], wq[64r+c,m] ) )
// wq = clamp(rintf(w*scale), -7, 7), scale = fl32(15/(fl32(max-min)+1e-9f))
//
// Main path: bf16 MFMA with x split hi/lo (w int4 exact in bf16).
// |mfma_dot - ref_fp32_chain| < ~2e-3; dots with |s| < TAU=0.03 recomputed
// bit-exactly (sequential fp32, ascending c, separate mul/add -- R4 body).
// R3->R4: per-dot global atomics -> per-block LDS queue (611 -> 93 us).
// R5 FAILED: rewritten k_fix body flipped a sign; reverted (proven R4 body).
// R6: k_fix grid 64->512. R7: barrier-free gather k_main.
// R8: depth-1 B prefetch + fix folded into k_main tail.
// R9 REGRESSED: rolled scalar self-reduction in k_prep; R10 fixed it
//     (float4 x4 unroll). k_main stable at 63.5 us, MfmaUtil 11 / VALU 41 /
//     occ 30% -- grid 1024 blocks = 4096 waves vs 8192 slots: 50% hard cap.
// R11: m-split grid (256,8): block = 64n x 32m, 2048 blocks = 8192 waves
//     (100% occupancy ceiling). Per-dot math bitwise identical (same frags,
//     same MFMA order) -> absmax stays 0. B-gather VALU duplicated 8x/n
//     instead of 4x (total ~1.2x) but issue slots double.

#define TAU 0.03f
#define HITCAP 2048

typedef short short8 __attribute__((ext_vector_type(8)));
typedef float f32x4 __attribute__((ext_vector_type(4)));
typedef unsigned int uv4 __attribute__((ext_vector_type(4)));

__device__ __forceinline__ unsigned short bf16rn(float v) {
    unsigned u = __float_as_uint(v);
    unsigned r = u + 0x7fffu + ((u >> 16) & 1u);
    return (unsigned short)(r >> 16);
}

// ---------------- prep (single dispatch, R10 proven):
//   blocks 0..2047   : zero-padded hi/lo bf16 planes
//   blocks 2048..2191: weight quant into MFMA A-frag order (self-computed scale);
//                      block 2048 publishes scale for k_main's fix tail.
__global__ __launch_bounds__(256) void k_prep(const float* __restrict__ w,
                                              const float* __restrict__ inp,
                                              float* __restrict__ scale_ws,
                                              unsigned* __restrict__ xpk,
                                              uv4* __restrict__ wqb) {
    const int t = threadIdx.x;
    if (blockIdx.x < 2048) {
        int bc = blockIdx.x;                   // b*128 + cin
        const float* src = inp + (size_t)bc * 1024;
        unsigned* dst = xpk + (size_t)bc * 1156;
        #pragma unroll
        for (int i = 0; i < 5; ++i) {
            int idx = t + i * 256;
            if (idx < 1156) {
                int yy = idx / 34, xx = idx - yy * 34;
                float v = 0.0f;
                int ys = yy - 1, xs_ = xx - 1;
                if ((unsigned)ys < 32u && (unsigned)xs_ < 32u) v = src[ys * 32 + xs_];
                unsigned short h = bf16rn(v);
                float hf = __uint_as_float((unsigned)h << 16);
                unsigned short l = bf16rn(v - hf);
                dst[idx] = (unsigned)h | ((unsigned)l << 16);
            }
        }
    } else {
        // ---- self-reduce min/max over the whole weight array (float4 x4,
        //      independent accumulators; selection -> order-independent) ----
        const float4* __restrict__ w4 = (const float4*)w;   // 73728 float4s
        float4 mn0 = w4[t], mx0 = mn0;
        float4 mn1 = mn0, mx1 = mn0, mn2 = mn0, mx2 = mn0, mn3 = mn0, mx3 = mn0;
        for (int i = t + 1024; i < 73728; i += 1024) {
            float4 a = w4[i];
            float4 b = w4[i + 256];
            float4 c = w4[i + 512];
            float4 d = w4[i + 768];
            mn0.x = fminf(mn0.x, a.x); mn0.y = fminf(mn0.y, a.y);
            mn0.z = fminf(mn0.z, a.z); mn0.w = fminf(mn0.w, a.w);
            mx0.x = fmaxf(mx0.x, a.x); mx0.y = fmaxf(mx0.y, a.y);
            mx0.z = fmaxf(mx0.z, a.z); mx0.w = fmaxf(mx0.w, a.w);
            mn1.x = fminf(mn1.x, b.x); mn1.y = fminf(mn1.y, b.y);
            mn1.z = fminf(mn1.z, b.z); mn1.w = fminf(mn1.w, b.w);
            mx1.x = fmaxf(mx1.x, b.x); mx1.y = fmaxf(mx1.y, b.y);
            mx1.z = fmaxf(mx1.z, b.z); mx1.w = fmaxf(mx1.w, b.w);
            mn2.x = fminf(mn2.x, c.x); mn2.y = fminf(mn2.y, c.y);
            mn2.z = fminf(mn2.z, c.z); mn2.w = fminf(mn2.w, c.w);
            mx2.x = fmaxf(mx2.x, c.x); mx2.y = fmaxf(mx2.y, c.y);
            mx2.z = fmaxf(mx2.z, c.z); mx2.w = fmaxf(mx2.w, c.w);
            mn3.x = fminf(mn3.x, d.x); mn3.y = fminf(mn3.y, d.y);
            mn3.z = fminf(mn3.z, d.z); mn3.w = fminf(mn3.w, d.w);
            mx3.x = fmaxf(mx3.x, d.x); mx3.y = fmaxf(mx3.y, d.y);
            mx3.z = fmaxf(mx3.z, d.z); mx3.w = fmaxf(mx3.w, d.w);
        }
        {
            float4 b = w4[t + 256], c = w4[t + 512], d = w4[t + 768];
            mn1.x = fminf(mn1.x, b.x); mn1.y = fminf(mn1.y, b.y);
            mn1.z = fminf(mn1.z, b.z); mn1.w = fminf(mn1.w, b.w);
            mx1.x = fmaxf(mx1.x, b.x); mx1.y = fmaxf(mx1.y, b.y);
            mx1.z = fmaxf(mx1.z, b.z); mx1.w = fmaxf(mx1.w, b.w);
            mn2.x = fminf(mn2.x, c.x); mn2.y = fminf(mn2.y, c.y);
            mn2.z = fminf(mn2.z, c.z); mn2.w = fminf(mn2.w, c.w);
            mx2.x = fmaxf(mx2.x, c.x); mx2.y = fmaxf(mx2.y, c.y);
            mx2.z = fmaxf(mx2.z, c.z); mx2.w = fmaxf(mx2.w, c.w);
            mn3.x = fminf(mn3.x, d.x); mn3.y = fminf(mn3.y, d.y);
            mn3.z = fminf(mn3.z, d.z); mn3.w = fminf(mn3.w, d.w);
            mx3.x = fmaxf(mx3.x, d.x); mx3.y = fmaxf(mx3.y, d.y);
            mx3.z = fmaxf(mx3.z, d.z); mx3.w = fmaxf(mx3.w, d.w);
        }
        mn0.x = fminf(fminf(mn0.x, mn1.x), fminf(mn2.x, mn3.x));
        mn0.y = fminf(fminf(mn0.y, mn1.y), fminf(mn2.y, mn3.y));
        mn0.z = fminf(fminf(mn0.z, mn1.z), fminf(mn2.z, mn3.z));
        mn0.w = fminf(fminf(mn0.w, mn1.w), fminf(mn2.w, mn3.w));
        mx0.x = fmaxf(fmaxf(mx0.x, mx1.x), fmaxf(mx2.x, mx3.x));
        mx0.y = fmaxf(fmaxf(mx0.y, mx1.y), fmaxf(mx2.y, mx3.y));
        mx0.z = fmaxf(fmaxf(mx0.z, mx1.z), fmaxf(mx2.z, mx3.z));
        mx0.w = fmaxf(fmaxf(mx0.w, mx1.w), fmaxf(mx2.w, mx3.w));
        float vmin = fminf(fminf(mn0.x, mn0.y), fminf(mn0.z, mn0.w));
        float vmax = fmaxf(fmaxf(mx0.x, mx0.y), fmaxf(mx0.z, mx0.w));
        #pragma unroll
        for (int off = 32; off > 0; off >>= 1) {
            vmin = fminf(vmin, __shfl_down(vmin, off, 64));
            vmax = fmaxf(vmax, __shfl_down(vmax, off, 64));
        }
        __shared__ float smin[4], smax[4], sca;
        int wave = t >> 6;
        if ((t & 63) == 0) { smin[wave] = vmin; smax[wave] = vmax; }
        __syncthreads();
        if (t == 0) {
            #pragma unroll
            for (int i = 1; i < 4; i++) {
                vmin = fminf(vmin, smin[i]);
                vmax = fmaxf(vmax, smax[i]);
            }
            float tt = __fadd_rn(__fsub_rn(vmax, vmin), 1e-9f);
            sca = __fdiv_rn(15.0f, tt);
            if (blockIdx.x == 2048) *scale_ws = sca;
        }
        __syncthreads();
        float s = sca;

        // ---- quantize into MFMA A-fragment order ----
        // slot = ((g4*18 + r)*8 + mt*2 + khalf)*64 + lane ; 8 bf16 per slot
        int slot = (blockIdx.x - 2048) * 256 + t;   // 36864 total
        int lane = slot & 63;
        int sub = slot >> 6;
        int khalf = sub & 1;
        int mt = (sub >> 1) & 3;
        int gr = sub >> 3;                 // g4*18 + r
        int g = gr / 18, r = gr - g * 18;
        int m = g * 64 + mt * 16 + (lane & 15);
        int dbase = r * 64 + khalf * 32 + (lane >> 4) * 8;
        const float* wp = w + (size_t)m * 1152 + dbase;
        unsigned o[4];
        #pragma unroll
        for (int p = 0; p < 4; ++p) {
            float q0 = rintf(__fmul_rn(wp[2 * p], s));
            float q1 = rintf(__fmul_rn(wp[2 * p + 1], s));
            q0 = fminf(fmaxf(q0, -7.0f), 7.0f);
            q1 = fminf(fmaxf(q1, -7.0f), 7.0f);
            o[p] = (unsigned)bf16rn(q0) | ((unsigned)bf16rn(q1) << 16);
        }
        uv4 v; v.x = o[0]; v.y = o[1]; v.z = o[2]; v.w = o[3];
        wqb[slot] = v;
    }
}

// ---------------- main: barrier-free gather GEMM, 64n x 32m blocks ----------------
__global__ __launch_bounds__(256) void k_main(const unsigned* __restrict__ xpk,
                                              const uv4* __restrict__ wqb,
                                              const float* __restrict__ inp,
                                              const float* __restrict__ weight,
                                              const float* __restrict__ scale_ws,
                                              float* __restrict__ out) {
    __shared__ int ofs_s[1152];        // plane offset for each k: cin*1156+kh*34+kw
    __shared__ unsigned hitbuf[HITCAP];
    __shared__ unsigned hitcnt;

    const int t = threadIdx.x;
    if (t == 0) hitcnt = 0u;
    const float sc = *scale_ws;        // uniform scalar load (k_prep published it)
    for (int k = t; k < 1152; k += 256) {
        int cin = k / 9;
        int rem = k - cin * 9;
        int kh = rem / 3;
        int kw = rem - kh * 3;
        ofs_s[k] = cin * 1156 + kh * 34 + kw;
    }
    __syncthreads();                   // covers hitcnt init + ofs_s

    const int lane = t & 63;
    const int wv = t >> 6;             // wave id = n-subtile (4 x 16n = 64n)
    const int quad = lane >> 4;
    const int nl = lane & 15;
    const int n0 = blockIdx.x * 64;
    const int g8 = blockIdx.y;         // 32-m group (0..7)
    const int g4 = g8 >> 1;            // 64-m group in wqb layout
    const int mth = (g8 & 1) * 2;      // mt offset within g4
    const int b = n0 >> 10;

    // wave's image-position base (16 consecutive positions within one row)
    const int sy_w = ((n0 & 1023) >> 5) + (wv >> 1);
    const int col0 = (wv & 1) * 16;
    const unsigned* __restrict__ xw =
        xpk + (size_t)b * (128 * 1156) + sy_w * 34 + col0 + nl;
    const uv4* __restrict__ aw = wqb + (size_t)g4 * (18 * 512) + lane;

    int counts[2][4] = {};

    // ---- prologue: prefetch chunk 0's B-gather u32s into registers ----
    unsigned pb[16];
    #pragma unroll
    for (int q2 = 0; q2 < 16; ++q2) {
        int k = (q2 >> 3) * 32 + quad * 8 + (q2 & 7);
        pb[q2] = xw[ofs_s[k]];
    }

    for (int r = 0; r < 18; ++r) {
        // consume prefetched, issue next chunk's gathers immediately
        unsigned cb[16];
        #pragma unroll
        for (int q2 = 0; q2 < 16; ++q2) cb[q2] = pb[q2];
        if (r < 17) {
            #pragma unroll
            for (int q2 = 0; q2 < 16; ++q2) {
                int k = (r + 1) * 64 + (q2 >> 3) * 32 + quad * 8 + (q2 & 7);
                pb[q2] = xw[ofs_s[k]];
            }
        }

        // ---- repack current B (split packed hi|lo) ----
        short8 bhi[2], blo[2];
        #pragma unroll
        for (int kh2 = 0; kh2 < 2; ++kh2) {
            union { unsigned d[4]; short8 v; } H, L;
            #pragma unroll
            for (int p = 0; p < 4; ++p) {
                unsigned ua = cb[kh2 * 8 + 2 * p], ub = cb[kh2 * 8 + 2 * p + 1];
                H.d[p] = (ua & 0xffffu) | (ub << 16);
                L.d[p] = (ua >> 16) | (ub & 0xffff0000u);
            }
            bhi[kh2] = H.v;
            blo[kh2] = L.v;
        }

        // ---- per m-subtile (2 of them): A frags from global, 4 MFMAs, checks ----
        #pragma unroll
        for (int mtl = 0; mtl < 2; ++mtl) {
            const int mt = mth + mtl;
            short8 af0 = __builtin_bit_cast(short8, aw[r * 512 + (mt * 2 + 0) * 64]);
            short8 af1 = __builtin_bit_cast(short8, aw[r * 512 + (mt * 2 + 1) * 64]);
            f32x4 acc = {0.0f, 0.0f, 0.0f, 0.0f};
            acc = __builtin_amdgcn_mfma_f32_16x16x32_bf16(af0, bhi[0], acc, 0, 0, 0);
            acc = __builtin_amdgcn_mfma_f32_16x16x32_bf16(af1, bhi[1], acc, 0, 0, 0);
            acc = __builtin_amdgcn_mfma_f32_16x16x32_bf16(af0, blo[0], acc, 0, 0, 0);
            acc = __builtin_amdgcn_mfma_f32_16x16x32_bf16(af1, blo[1], acc, 0, 0, 0);
            #pragma unroll
            for (int i = 0; i < 4; ++i) {
                float s = acc[i];
                int ge = (s >= 0.0f) ? 1 : 0;
                counts[mtl][i] += ge;
                if (__builtin_fabsf(s) < TAU) {
                    unsigned idx = atomicAdd(&hitcnt, 1u);   // LDS atomic: fast, rare
                    if (idx < (unsigned)HITCAP) {
                        unsigned m = (unsigned)(g4 * 64 + mt * 16 + quad * 4 + i);
                        unsigned n = (unsigned)(n0 + wv * 16 + nl);
                        hitbuf[idx] = n | ((unsigned)r << 14) | (m << 19) | ((unsigned)ge << 27);
                    }
                }
            }
        }
    }

    // ---- epilogue: C/D layout col=lane&15 (n), row=quad*4+reg (m) ----
    {
        const int n = n0 + wv * 16 + nl;
        const int p = n & 1023;
        #pragma unroll
        for (int mtl = 0; mtl < 2; ++mtl)
            #pragma unroll
            for (int i = 0; i < 4; ++i) {
                int m = g4 * 64 + (mth + mtl) * 16 + quad * 4 + i;
                out[(((size_t)(b * 256 + m)) << 10) + p] = (float)counts[mtl][i];
            }
    }

    // ---- in-block fixup of this block's own hits (R4 k_fix body, verbatim math) ----
    __syncthreads();
    unsigned tot = hitcnt;
    if (tot > (unsigned)HITCAP) tot = (unsigned)HITCAP;
    for (unsigned i = t; i < tot; i += 256) {
        unsigned u = hitbuf[i];
        int n = u & 16383;
        int r = (u >> 14) & 31;
        int m = (u >> 19) & 255;
        int bit = (u >> 27) & 1;
        int bb = n >> 10, p = n & 1023, y = p >> 5, x = p & 31;
        const float* ib = inp + (size_t)bb * (128 * 32 * 32);
        const float* wp = weight + (size_t)m * 1152;
        float s = 0.0f;
        int d = r * 64;
        for (int c = 0; c < 64; ++c, ++d) {
            int ci = d / 9, rem = d - ci * 9;
            int kh = rem / 3, kw = rem - kh * 3;
            int yy = y + kh - 1, xx = x + kw - 1;
            float xv = 0.0f;
            if ((unsigned)yy < 32u && (unsigned)xx < 32u)
                xv = ib[(ci * 32 + yy) * 32 + xx];
            float q = rintf(__fmul_rn(wp[d], sc));
            q = fminf(fmaxf(q, -7.0f), 7.0f);
            s = __fadd_rn(s, __fmul_rn(xv, q));
        }
        int nb = (s >= 0.0f) ? 1 : 0;
        if (nb != bit)
            atomicAdd(&out[(((size_t)(bb * 256 + m)) << 10) + p], nb ? 1.0f : -1.0f);
    }
}

extern "C" void kernel_launch(void* const* d_in, const int* in_sizes, int n_in,
                              void* d_out, int out_size, void* d_ws, size_t ws_size,
                              hipStream_t stream) {
    const float* inp    = (const float*)d_in[0];   // [16,128,32,32]
    const float* weight = (const float*)d_in[1];   // [256,128,3,3]
    float* out = (float*)d_out;                    // [16,256,32,32]

    char* ws = (char*)d_ws;
    float*    scale = (float*)(ws + 0);
    uv4*      wqb   = (uv4*)(ws + 1024);          // 589,824 B
    unsigned* xpk   = (unsigned*)(ws + 590848);   // 9,469,952 B

    k_prep<<<2192, 256, 0, stream>>>(weight, inp, scale, xpk, wqb);

    dim3 grid(256, 8);   // (N/64, M/32) -> 2048 blocks = 8192 waves
    k_main<<<grid, 256, 0, stream>>>(xpk, wqb, inp, weight, scale, out);
}

// Round 12
// 147.625 us; speedup vs baseline: 1.1690x; 1.1690x over previous
//
#include <hip/hip_runtime.h>

// ONN conv2d: B=16, Cin=128, H=W=32, Cout=256, k=3 (pad=1, stride=1)
// N=16384 positions, D=1152=18*64 chunks of VEC=64, M=256.
// out[n,m] = sum_r sign01( dot_c( x[n,64r+c], wq[64r+c,m] ) )
// wq = clamp(rintf(w*scale), -7, 7), scale = fl32(15/(fl32(max-min)+1e-9f))
//
// Main path: bf16 MFMA with x split hi/lo (w int4 exact in bf16).
// |mfma_dot - ref_fp32_chain| < ~2e-3; dots with |s| < TAU=0.03 recomputed
// bit-exactly (sequential fp32, ascending c, separate mul/add -- R4 body).
// R3->R4: per-dot global atomics -> per-block LDS queue (611 -> 93 us).
// R5 FAILED: rewritten k_fix body flipped a sign; reverted (proven R4 body).
// R6: k_fix grid 64->512. R7: barrier-free gather k_main.
// R8: depth-1 B prefetch + fix folded into k_main tail.
// R9 REGRESSED: rolled scalar self-reduction; R10 fixed (float4 x4 unroll),
//     k_main 63.5 us @ MfmaUtil 11 / VALU 41.
// R11 REGRESSED (82 us): m-split grid (256,8) duplicated B-gather+repack
//     (FETCH 24->41 MB), occupancy unchanged -- wave-slot ceiling was NOT
//     the limiter. Reverted.
// R12: R10 structure + depth-1 prefetch of BOTH A-frags and B-gathers
//     (A loads were issue-and-consume -- the unhidden latency). Iter order:
//     repack -> 16 MFMAs -> issue r+1 loads -> checks. launch_bounds(256,4).

#define TAU 0.03f
#define HITCAP 2048

typedef short short8 __attribute__((ext_vector_type(8)));
typedef float f32x4 __attribute__((ext_vector_type(4)));
typedef unsigned int uv4 __attribute__((ext_vector_type(4)));

__device__ __forceinline__ unsigned short bf16rn(float v) {
    unsigned u = __float_as_uint(v);
    unsigned r = u + 0x7fffu + ((u >> 16) & 1u);
    return (unsigned short)(r >> 16);
}

// ---------------- prep (single dispatch, R10 proven):
//   blocks 0..2047   : zero-padded hi/lo bf16 planes
//   blocks 2048..2191: weight quant into MFMA A-frag order (self-computed scale);
//                      block 2048 publishes scale for k_main's fix tail.
__global__ __launch_bounds__(256) void k_prep(const float* __restrict__ w,
                                              const float* __restrict__ inp,
                                              float* __restrict__ scale_ws,
                                              unsigned* __restrict__ xpk,
                                              uv4* __restrict__ wqb) {
    const int t = threadIdx.x;
    if (blockIdx.x < 2048) {
        int bc = blockIdx.x;                   // b*128 + cin
        const float* src = inp + (size_t)bc * 1024;
        unsigned* dst = xpk + (size_t)bc * 1156;
        #pragma unroll
        for (int i = 0; i < 5; ++i) {
            int idx = t + i * 256;
            if (idx < 1156) {
                int yy = idx / 34, xx = idx - yy * 34;
                float v = 0.0f;
                int ys = yy - 1, xs_ = xx - 1;
                if ((unsigned)ys < 32u && (unsigned)xs_ < 32u) v = src[ys * 32 + xs_];
                unsigned short h = bf16rn(v);
                float hf = __uint_as_float((unsigned)h << 16);
                unsigned short l = bf16rn(v - hf);
                dst[idx] = (unsigned)h | ((unsigned)l << 16);
            }
        }
    } else {
        // ---- self-reduce min/max over the whole weight array (float4 x4,
        //      independent accumulators; selection -> order-independent) ----
        const float4* __restrict__ w4 = (const float4*)w;   // 73728 float4s
        float4 mn0 = w4[t], mx0 = mn0;
        float4 mn1 = mn0, mx1 = mn0, mn2 = mn0, mx2 = mn0, mn3 = mn0, mx3 = mn0;
        for (int i = t + 1024; i < 73728; i += 1024) {
            float4 a = w4[i];
            float4 b = w4[i + 256];
            float4 c = w4[i + 512];
            float4 d = w4[i + 768];
            mn0.x = fminf(mn0.x, a.x); mn0.y = fminf(mn0.y, a.y);
            mn0.z = fminf(mn0.z, a.z); mn0.w = fminf(mn0.w, a.w);
            mx0.x = fmaxf(mx0.x, a.x); mx0.y = fmaxf(mx0.y, a.y);
            mx0.z = fmaxf(mx0.z, a.z); mx0.w = fmaxf(mx0.w, a.w);
            mn1.x = fminf(mn1.x, b.x); mn1.y = fminf(mn1.y, b.y);
            mn1.z = fminf(mn1.z, b.z); mn1.w = fminf(mn1.w, b.w);
            mx1.x = fmaxf(mx1.x, b.x); mx1.y = fmaxf(mx1.y, b.y);
            mx1.z = fmaxf(mx1.z, b.z); mx1.w = fmaxf(mx1.w, b.w);
            mn2.x = fminf(mn2.x, c.x); mn2.y = fminf(mn2.y, c.y);
            mn2.z = fminf(mn2.z, c.z); mn2.w = fminf(mn2.w, c.w);
            mx2.x = fmaxf(mx2.x, c.x); mx2.y = fmaxf(mx2.y, c.y);
            mx2.z = fmaxf(mx2.z, c.z); mx2.w = fmaxf(mx2.w, c.w);
            mn3.x = fminf(mn3.x, d.x); mn3.y = fminf(mn3.y, d.y);
            mn3.z = fminf(mn3.z, d.z); mn3.w = fminf(mn3.w, d.w);
            mx3.x = fmaxf(mx3.x, d.x); mx3.y = fmaxf(mx3.y, d.y);
            mx3.z = fmaxf(mx3.z, d.z); mx3.w = fmaxf(mx3.w, d.w);
        }
        {
            float4 b = w4[t + 256], c = w4[t + 512], d = w4[t + 768];
            mn1.x = fminf(mn1.x, b.x); mn1.y = fminf(mn1.y, b.y);
            mn1.z = fminf(mn1.z, b.z); mn1.w = fminf(mn1.w, b.w);
            mx1.x = fmaxf(mx1.x, b.x); mx1.y = fmaxf(mx1.y, b.y);
            mx1.z = fmaxf(mx1.z, b.z); mx1.w = fmaxf(mx1.w, b.w);
            mn2.x = fminf(mn2.x, c.x); mn2.y = fminf(mn2.y, c.y);
            mn2.z = fminf(mn2.z, c.z); mn2.w = fminf(mn2.w, c.w);
            mx2.x = fmaxf(mx2.x, c.x); mx2.y = fmaxf(mx2.y, c.y);
            mx2.z = fmaxf(mx2.z, c.z); mx2.w = fmaxf(mx2.w, c.w);
            mn3.x = fminf(mn3.x, d.x); mn3.y = fminf(mn3.y, d.y);
            mn3.z = fminf(mn3.z, d.z); mn3.w = fminf(mn3.w, d.w);
            mx3.x = fmaxf(mx3.x, d.x); mx3.y = fmaxf(mx3.y, d.y);
            mx3.z = fmaxf(mx3.z, d.z); mx3.w = fmaxf(mx3.w, d.w);
        }
        mn0.x = fminf(fminf(mn0.x, mn1.x), fminf(mn2.x, mn3.x));
        mn0.y = fminf(fminf(mn0.y, mn1.y), fminf(mn2.y, mn3.y));
        mn0.z = fminf(fminf(mn0.z, mn1.z), fminf(mn2.z, mn3.z));
        mn0.w = fminf(fminf(mn0.w, mn1.w), fminf(mn2.w, mn3.w));
        mx0.x = fmaxf(fmaxf(mx0.x, mx1.x), fmaxf(mx2.x, mx3.x));
        mx0.y = fmaxf(fmaxf(mx0.y, mx1.y), fmaxf(mx2.y, mx3.y));
        mx0.z = fmaxf(fmaxf(mx0.z, mx1.z), fmaxf(mx2.z, mx3.z));
        mx0.w = fmaxf(fmaxf(mx0.w, mx1.w), fmaxf(mx2.w, mx3.w));
        float vmin = fminf(fminf(mn0.x, mn0.y), fminf(mn0.z, mn0.w));
        float vmax = fmaxf(fmaxf(mx0.x, mx0.y), fmaxf(mx0.z, mx0.w));
        #pragma unroll
        for (int off = 32; off > 0; off >>= 1) {
            vmin = fminf(vmin, __shfl_down(vmin, off, 64));
            vmax = fmaxf(vmax, __shfl_down(vmax, off, 64));
        }
        __shared__ float smin[4], smax[4], sca;
        int wave = t >> 6;
        if ((t & 63) == 0) { smin[wave] = vmin; smax[wave] = vmax; }
        __syncthreads();
        if (t == 0) {
            #pragma unroll
            for (int i = 1; i < 4; i++) {
                vmin = fminf(vmin, smin[i]);
                vmax = fmaxf(vmax, smax[i]);
            }
            float tt = __fadd_rn(__fsub_rn(vmax, vmin), 1e-9f);
            sca = __fdiv_rn(15.0f, tt);
            if (blockIdx.x == 2048) *scale_ws = sca;
        }
        __syncthreads();
        float s = sca;

        // ---- quantize into MFMA A-fragment order ----
        // slot = ((g*18 + r)*8 + mt*2 + khalf)*64 + lane ; 8 bf16 per slot
        int slot = (blockIdx.x - 2048) * 256 + t;   // 36864 total
        int lane = slot & 63;
        int sub = slot >> 6;
        int khalf = sub & 1;
        int mt = (sub >> 1) & 3;
        int gr = sub >> 3;                 // g*18 + r
        int g = gr / 18, r = gr - g * 18;
        int m = g * 64 + mt * 16 + (lane & 15);
        int dbase = r * 64 + khalf * 32 + (lane >> 4) * 8;
        const float* wp = w + (size_t)m * 1152 + dbase;
        unsigned o[4];
        #pragma unroll
        for (int p = 0; p < 4; ++p) {
            float q0 = rintf(__fmul_rn(wp[2 * p], s));
            float q1 = rintf(__fmul_rn(wp[2 * p + 1], s));
            q0 = fminf(fmaxf(q0, -7.0f), 7.0f);
            q1 = fminf(fmaxf(q1, -7.0f), 7.0f);
            o[p] = (unsigned)bf16rn(q0) | ((unsigned)bf16rn(q1) << 16);
        }
        uv4 v; v.x = o[0]; v.y = o[1]; v.z = o[2]; v.w = o[3];
        wqb[slot] = v;
    }
}

// ---------------- main: barrier-free gather GEMM, A+B depth-1 prefetch ----------------
__global__ __launch_bounds__(256, 4) void k_main(const unsigned* __restrict__ xpk,
                                                 const uv4* __restrict__ wqb,
                                                 const float* __restrict__ inp,
                                                 const float* __restrict__ weight,
                                                 const float* __restrict__ scale_ws,
                                                 float* __restrict__ out) {
    __shared__ int ofs_s[1152];        // plane offset for each k: cin*1156+kh*34+kw
    __shared__ unsigned hitbuf[HITCAP];
    __shared__ unsigned hitcnt;

    const int t = threadIdx.x;
    if (t == 0) hitcnt = 0u;
    const float sc = *scale_ws;        // uniform scalar load (k_prep published it)
    for (int k = t; k < 1152; k += 256) {
        int cin = k / 9;
        int rem = k - cin * 9;
        int kh = rem / 3;
        int kw = rem - kh * 3;
        ofs_s[k] = cin * 1156 + kh * 34 + kw;
    }
    __syncthreads();                   // covers hitcnt init + ofs_s

    const int lane = t & 63;
    const int wv = t >> 6;             // wave id = n-subtile
    const int quad = lane >> 4;
    const int nl = lane & 15;
    const int n0 = blockIdx.x * 64;
    const int g = blockIdx.y;
    const int b = n0 >> 10;

    // wave's image-position base (16 consecutive positions within one row)
    const int sy_w = ((n0 & 1023) >> 5) + (wv >> 1);
    const int col0 = (wv & 1) * 16;
    const unsigned* __restrict__ xw =
        xpk + (size_t)b * (128 * 1156) + sy_w * 34 + col0 + nl;
    const uv4* __restrict__ aw = wqb + (size_t)g * (18 * 512) + lane;

    int counts[4][4] = {};

    // ---- prologue: prefetch chunk 0's B-gather u32s AND A-frag dwords ----
    unsigned pb[16];
    uv4 pa[8];
    #pragma unroll
    for (int q2 = 0; q2 < 16; ++q2) {
        int k = (q2 >> 3) * 32 + quad * 8 + (q2 & 7);
        pb[q2] = xw[ofs_s[k]];
    }
    #pragma unroll
    for (int j = 0; j < 8; ++j) pa[j] = aw[j * 64];

    for (int r = 0; r < 18; ++r) {
        // ---- repack current B (split packed hi|lo) from pb ----
        short8 bhi[2], blo[2];
        #pragma unroll
        for (int kh2 = 0; kh2 < 2; ++kh2) {
            union { unsigned d[4]; short8 v; } H, L;
            #pragma unroll
            for (int p = 0; p < 4; ++p) {
                unsigned ua = pb[kh2 * 8 + 2 * p], ub = pb[kh2 * 8 + 2 * p + 1];
                H.d[p] = (ua & 0xffffu) | (ub << 16);
                L.d[p] = (ua >> 16) | (ub & 0xffff0000u);
            }
            bhi[kh2] = H.v;
            blo[kh2] = L.v;
        }
        short8 af[8];
        #pragma unroll
        for (int j = 0; j < 8; ++j) af[j] = __builtin_bit_cast(short8, pa[j]);

        // ---- issue all 16 MFMAs (independent chains across mt) ----
        f32x4 acc[4];
        #pragma unroll
        for (int mt = 0; mt < 4; ++mt) {
            f32x4 a0 = {0.0f, 0.0f, 0.0f, 0.0f};
            a0 = __builtin_amdgcn_mfma_f32_16x16x32_bf16(af[mt * 2 + 0], bhi[0], a0, 0, 0, 0);
            a0 = __builtin_amdgcn_mfma_f32_16x16x32_bf16(af[mt * 2 + 1], bhi[1], a0, 0, 0, 0);
            a0 = __builtin_amdgcn_mfma_f32_16x16x32_bf16(af[mt * 2 + 0], blo[0], a0, 0, 0, 0);
            a0 = __builtin_amdgcn_mfma_f32_16x16x32_bf16(af[mt * 2 + 1], blo[1], a0, 0, 0, 0);
            acc[mt] = a0;
        }

        // ---- issue next chunk's loads while MFMAs are in flight ----
        if (r < 17) {
            #pragma unroll
            for (int q2 = 0; q2 < 16; ++q2) {
                int k = (r + 1) * 64 + (q2 >> 3) * 32 + quad * 8 + (q2 & 7);
                pb[q2] = xw[ofs_s[k]];
            }
            #pragma unroll
            for (int j = 0; j < 8; ++j) pa[j] = aw[(r + 1) * 512 + j * 64];
        }

        // ---- binarize, count, borderline -> LDS queue ----
        #pragma unroll
        for (int mt = 0; mt < 4; ++mt) {
            #pragma unroll
            for (int i = 0; i < 4; ++i) {
                float s = acc[mt][i];
                int ge = (s >= 0.0f) ? 1 : 0;
                counts[mt][i] += ge;
                if (__builtin_fabsf(s) < TAU) {
                    unsigned idx = atomicAdd(&hitcnt, 1u);   // LDS atomic: fast, rare
                    if (idx < (unsigned)HITCAP) {
                        unsigned m = (unsigned)(g * 64 + mt * 16 + quad * 4 + i);
                        unsigned n = (unsigned)(n0 + wv * 16 + nl);
                        hitbuf[idx] = n | ((unsigned)r << 14) | (m << 19) | ((unsigned)ge << 27);
                    }
                }
            }
        }
    }

    // ---- epilogue: C/D layout col=lane&15 (n), row=quad*4+reg (m) ----
    {
        const int n = n0 + wv * 16 + nl;
        const int p = n & 1023;
        #pragma unroll
        for (int mt = 0; mt < 4; ++mt)
            #pragma unroll
            for (int i = 0; i < 4; ++i) {
                int m = g * 64 + mt * 16 + quad * 4 + i;
                out[(((size_t)(b * 256 + m)) << 10) + p] = (float)counts[mt][i];
            }
    }

    // ---- in-block fixup of this block's own hits (R4 k_fix body, verbatim math) ----
    __syncthreads();
    unsigned tot = hitcnt;
    if (tot > (unsigned)HITCAP) tot = (unsigned)HITCAP;
    for (unsigned i = t; i < tot; i += 256) {
        unsigned u = hitbuf[i];
        int n = u & 16383;
        int r = (u >> 14) & 31;
        int m = (u >> 19) & 255;
        int bit = (u >> 27) & 1;
        int bb = n >> 10, p = n & 1023, y = p >> 5, x = p & 31;
        const float* ib = inp + (size_t)bb * (128 * 32 * 32);
        const float* wp = weight + (size_t)m * 1152;
        float s = 0.0f;
        int d = r * 64;
        for (int c = 0; c < 64; ++c, ++d) {
            int ci = d / 9, rem = d - ci * 9;
            int kh = rem / 3, kw = rem - kh * 3;
            int yy = y + kh - 1, xx = x + kw - 1;
            float xv = 0.0f;
            if ((unsigned)yy < 32u && (unsigned)xx < 32u)
                xv = ib[(ci * 32 + yy) * 32 + xx];
            float q = rintf(__fmul_rn(wp[d], sc));
            q = fminf(fmaxf(q, -7.0f), 7.0f);
            s = __fadd_rn(s, __fmul_rn(xv, q));
        }
        int nb = (s >= 0.0f) ? 1 : 0;
        if (nb != bit)
            atomicAdd(&out[(((size_t)(bb * 256 + m)) << 10) + p], nb ? 1.0f : -1.0f);
    }
}

extern "C" void kernel_launch(void* const* d_in, const int* in_sizes, int n_in,
                              void* d_out, int out_size, void* d_ws, size_t ws_size,
                              hipStream_t stream) {
    const float* inp    = (const float*)d_in[0];   // [16,128,32,32]
    const float* weight = (const float*)d_in[1];   // [256,128,3,3]
    float* out = (float*)d_out;                    // [16,256,32,32]

    char* ws = (char*)d_ws;
    float*    scale = (float*)(ws + 0);
    uv4*      wqb   = (uv4*)(ws + 1024);          // 589,824 B
    unsigned* xpk   = (unsigned*)(ws + 590848);   // 9,469,952 B

    k_prep<<<2192, 256, 0, stream>>>(weight, inp, scale, xpk, wqb);

    dim3 grid(256, 4);   // (N/64, M/64) -> 1024 blocks
    k_main<<<grid, 256, 0, stream>>>(xpk, wqb, inp, weight, scale, out);
}

// Round 13
// 147.375 us; speedup vs baseline: 1.1710x; 1.0017x over previous
//
#include <hip/hip_runtime.h>

// ONN conv2d: B=16, Cin=128, H=W=32, Cout=256, k=3 (pad=1, stride=1)
// N=16384 positions, D=1152=18*64 chunks of VEC=64, M=256.
// out[n,m] = sum_r sign01( dot_c( x[n,64r+c], wq[64r+c,m] ) )
// wq = clamp(rintf(w*scale), -7, 7), scale = fl32(15/(fl32(max-min)+1e-9f))
//
// Main path: bf16 MFMA with x split hi/lo (w int4 exact in bf16).
// |mfma_dot - ref_fp32_chain| < ~2e-3; dots with |s| < TAU=0.03 recomputed
// bit-exactly (sequential fp32, ascending c, separate mul/add -- R4 body).
// R3->R4: per-dot global atomics -> per-block LDS queue (611 -> 93 us).
// R5 FAILED: rewritten k_fix body flipped a sign; reverted (proven R4 body).
// R6: k_fix grid 64->512. R7: barrier-free gather k_main.
// R8: depth-1 B prefetch + in-block fix tail. R9 regressed (rolled scalar
// reduction); R10 fixed it. R11 regressed (m-split dup'd staging). R12
// (A+B reg prefetch) neutral: k_main stuck 54-64 us across 3 structures.
// Invariant found: 12KB/wave-iter register-load traffic = ~22 us/CU TCP
// floor; A (8KB) is identical across the 4 waves of a block.
// R13: A delivery moved to the LDS pipe -- per-chunk 8KB A-slab staged once
// per block (double-buffered, ONE barrier/iter), consumed via ds_read_b128;
// TCP now carries only B + one staging pass. Clean test of the TCP theory.

#define TAU 0.03f
#define HITCAP 2048

typedef short short8 __attribute__((ext_vector_type(8)));
typedef float f32x4 __attribute__((ext_vector_type(4)));
typedef unsigned int uv4 __attribute__((ext_vector_type(4)));

__device__ __forceinline__ unsigned short bf16rn(float v) {
    unsigned u = __float_as_uint(v);
    unsigned r = u + 0x7fffu + ((u >> 16) & 1u);
    return (unsigned short)(r >> 16);
}

// ---------------- prep (single dispatch, R10 proven):
//   blocks 0..2047   : zero-padded hi/lo bf16 planes
//   blocks 2048..2191: weight quant into MFMA A-frag order (self-computed scale);
//                      block 2048 publishes scale for k_main's fix tail.
__global__ __launch_bounds__(256) void k_prep(const float* __restrict__ w,
                                              const float* __restrict__ inp,
                                              float* __restrict__ scale_ws,
                                              unsigned* __restrict__ xpk,
                                              uv4* __restrict__ wqb) {
    const int t = threadIdx.x;
    if (blockIdx.x < 2048) {
        int bc = blockIdx.x;                   // b*128 + cin
        const float* src = inp + (size_t)bc * 1024;
        unsigned* dst = xpk + (size_t)bc * 1156;
        #pragma unroll
        for (int i = 0; i < 5; ++i) {
            int idx = t + i * 256;
            if (idx < 1156) {
                int yy = idx / 34, xx = idx - yy * 34;
                float v = 0.0f;
                int ys = yy - 1, xs_ = xx - 1;
                if ((unsigned)ys < 32u && (unsigned)xs_ < 32u) v = src[ys * 32 + xs_];
                unsigned short h = bf16rn(v);
                float hf = __uint_as_float((unsigned)h << 16);
                unsigned short l = bf16rn(v - hf);
                dst[idx] = (unsigned)h | ((unsigned)l << 16);
            }
        }
    } else {
        // ---- self-reduce min/max over the whole weight array (float4 x4,
        //      independent accumulators; selection -> order-independent) ----
        const float4* __restrict__ w4 = (const float4*)w;   // 73728 float4s
        float4 mn0 = w4[t], mx0 = mn0;
        float4 mn1 = mn0, mx1 = mn0, mn2 = mn0, mx2 = mn0, mn3 = mn0, mx3 = mn0;
        for (int i = t + 1024; i < 73728; i += 1024) {
            float4 a = w4[i];
            float4 b = w4[i + 256];
            float4 c = w4[i + 512];
            float4 d = w4[i + 768];
            mn0.x = fminf(mn0.x, a.x); mn0.y = fminf(mn0.y, a.y);
            mn0.z = fminf(mn0.z, a.z); mn0.w = fminf(mn0.w, a.w);
            mx0.x = fmaxf(mx0.x, a.x); mx0.y = fmaxf(mx0.y, a.y);
            mx0.z = fmaxf(mx0.z, a.z); mx0.w = fmaxf(mx0.w, a.w);
            mn1.x = fminf(mn1.x, b.x); mn1.y = fminf(mn1.y, b.y);
            mn1.z = fminf(mn1.z, b.z); mn1.w = fminf(mn1.w, b.w);
            mx1.x = fmaxf(mx1.x, b.x); mx1.y = fmaxf(mx1.y, b.y);
            mx1.z = fmaxf(mx1.z, b.z); mx1.w = fmaxf(mx1.w, b.w);
            mn2.x = fminf(mn2.x, c.x); mn2.y = fminf(mn2.y, c.y);
            mn2.z = fminf(mn2.z, c.z); mn2.w = fminf(mn2.w, c.w);
            mx2.x = fmaxf(mx2.x, c.x); mx2.y = fmaxf(mx2.y, c.y);
            mx2.z = fmaxf(mx2.z, c.z); mx2.w = fmaxf(mx2.w, c.w);
            mn3.x = fminf(mn3.x, d.x); mn3.y = fminf(mn3.y, d.y);
            mn3.z = fminf(mn3.z, d.z); mn3.w = fminf(mn3.w, d.w);
            mx3.x = fmaxf(mx3.x, d.x); mx3.y = fmaxf(mx3.y, d.y);
            mx3.z = fmaxf(mx3.z, d.z); mx3.w = fmaxf(mx3.w, d.w);
        }
        {
            float4 b = w4[t + 256], c = w4[t + 512], d = w4[t + 768];
            mn1.x = fminf(mn1.x, b.x); mn1.y = fminf(mn1.y, b.y);
            mn1.z = fminf(mn1.z, b.z); mn1.w = fminf(mn1.w, b.w);
            mx1.x = fmaxf(mx1.x, b.x); mx1.y = fmaxf(mx1.y, b.y);
            mx1.z = fmaxf(mx1.z, b.z); mx1.w = fmaxf(mx1.w, b.w);
            mn2.x = fminf(mn2.x, c.x); mn2.y = fminf(mn2.y, c.y);
            mn2.z = fminf(mn2.z, c.z); mn2.w = fminf(mn2.w, c.w);
            mx2.x = fmaxf(mx2.x, c.x); mx2.y = fmaxf(mx2.y, c.y);
            mx2.z = fmaxf(mx2.z, c.z); mx2.w = fmaxf(mx2.w, c.w);
            mn3.x = fminf(mn3.x, d.x); mn3.y = fminf(mn3.y, d.y);
            mn3.z = fminf(mn3.z, d.z); mn3.w = fminf(mn3.w, d.w);
            mx3.x = fmaxf(mx3.x, d.x); mx3.y = fmaxf(mx3.y, d.y);
            mx3.z = fmaxf(mx3.z, d.z); mx3.w = fmaxf(mx3.w, d.w);
        }
        mn0.x = fminf(fminf(mn0.x, mn1.x), fminf(mn2.x, mn3.x));
        mn0.y = fminf(fminf(mn0.y, mn1.y), fminf(mn2.y, mn3.y));
        mn0.z = fminf(fminf(mn0.z, mn1.z), fminf(mn2.z, mn3.z));
        mn0.w = fminf(fminf(mn0.w, mn1.w), fminf(mn2.w, mn3.w));
        mx0.x = fmaxf(fmaxf(mx0.x, mx1.x), fmaxf(mx2.x, mx3.x));
        mx0.y = fmaxf(fmaxf(mx0.y, mx1.y), fmaxf(mx2.y, mx3.y));
        mx0.z = fmaxf(fmaxf(mx0.z, mx1.z), fmaxf(mx2.z, mx3.z));
        mx0.w = fmaxf(fmaxf(mx0.w, mx1.w), fmaxf(mx2.w, mx3.w));
        float vmin = fminf(fminf(mn0.x, mn0.y), fminf(mn0.z, mn0.w));
        float vmax = fmaxf(fmaxf(mx0.x, mx0.y), fmaxf(mx0.z, mx0.w));
        #pragma unroll
        for (int off = 32; off > 0; off >>= 1) {
            vmin = fminf(vmin, __shfl_down(vmin, off, 64));
            vmax = fmaxf(vmax, __shfl_down(vmax, off, 64));
        }
        __shared__ float smin[4], smax[4], sca;
        int wave = t >> 6;
        if ((t & 63) == 0) { smin[wave] = vmin; smax[wave] = vmax; }
        __syncthreads();
        if (t == 0) {
            #pragma unroll
            for (int i = 1; i < 4; i++) {
                vmin = fminf(vmin, smin[i]);
                vmax = fmaxf(vmax, smax[i]);
            }
            float tt = __fadd_rn(__fsub_rn(vmax, vmin), 1e-9f);
            sca = __fdiv_rn(15.0f, tt);
            if (blockIdx.x == 2048) *scale_ws = sca;
        }
        __syncthreads();
        float s = sca;

        // ---- quantize into MFMA A-fragment order ----
        // slot = ((g*18 + r)*8 + mt*2 + khalf)*64 + lane ; 8 bf16 per slot
        int slot = (blockIdx.x - 2048) * 256 + t;   // 36864 total
        int lane = slot & 63;
        int sub = slot >> 6;
        int khalf = sub & 1;
        int mt = (sub >> 1) & 3;
        int gr = sub >> 3;                 // g*18 + r
        int g = gr / 18, r = gr - g * 18;
        int m = g * 64 + mt * 16 + (lane & 15);
        int dbase = r * 64 + khalf * 32 + (lane >> 4) * 8;
        const float* wp = w + (size_t)m * 1152 + dbase;
        unsigned o[4];
        #pragma unroll
        for (int p = 0; p < 4; ++p) {
            float q0 = rintf(__fmul_rn(wp[2 * p], s));
            float q1 = rintf(__fmul_rn(wp[2 * p + 1], s));
            q0 = fminf(fmaxf(q0, -7.0f), 7.0f);
            q1 = fminf(fmaxf(q1, -7.0f), 7.0f);
            o[p] = (unsigned)bf16rn(q0) | ((unsigned)bf16rn(q1) << 16);
        }
        uv4 v; v.x = o[0]; v.y = o[1]; v.z = o[2]; v.w = o[3];
        wqb[slot] = v;
    }
}

// ---------------- main: gather GEMM, A via LDS double-buffer, B reg-prefetch ----------------
__global__ __launch_bounds__(256, 4) void k_main(const unsigned* __restrict__ xpk,
                                                 const uv4* __restrict__ wqb,
                                                 const float* __restrict__ inp,
                                                 const float* __restrict__ weight,
                                                 const float* __restrict__ scale_ws,
                                                 float* __restrict__ out) {
    __shared__ int ofs_s[1152];        // plane offset for each k: cin*1156+kh*34+kw
    __shared__ uv4 abuf[2][512];       // A-slab double buffer (2 x 8 KB)
    __shared__ unsigned hitbuf[HITCAP];
    __shared__ unsigned hitcnt;

    const int t = threadIdx.x;
    if (t == 0) hitcnt = 0u;
    const float sc = *scale_ws;        // uniform scalar load (k_prep published it)
    for (int k = t; k < 1152; k += 256) {
        int cin = k / 9;
        int rem = k - cin * 9;
        int kh = rem / 3;
        int kw = rem - kh * 3;
        ofs_s[k] = cin * 1156 + kh * 34 + kw;
    }

    const int lane = t & 63;
    const int wv = t >> 6;             // wave id = n-subtile
    const int quad = lane >> 4;
    const int nl = lane & 15;
    const int n0 = blockIdx.x * 64;
    const int g = blockIdx.y;
    const int b = n0 >> 10;

    // wave's image-position base (16 consecutive positions within one row)
    const int sy_w = ((n0 & 1023) >> 5) + (wv >> 1);
    const int col0 = (wv & 1) * 16;
    const unsigned* __restrict__ xw =
        xpk + (size_t)b * (128 * 1156) + sy_w * 34 + col0 + nl;
    const uv4* __restrict__ awg = wqb + (size_t)g * (18 * 512);

    int counts[4][4] = {};

    // ---- prologue: stage A(0) slab into buf0; prefetch B(0) gathers ----
    {
        uv4 a0 = awg[t];
        uv4 a1 = awg[t + 256];
        abuf[0][t] = a0;
        abuf[0][t + 256] = a1;
    }
    __syncthreads();                   // ofs_s + hitcnt + abuf[0] ready
    unsigned pb[16];
    #pragma unroll
    for (int q2 = 0; q2 < 16; ++q2) {
        int k = (q2 >> 3) * 32 + quad * 8 + (q2 & 7);
        pb[q2] = xw[ofs_s[k]];
    }

    for (int r = 0; r < 18; ++r) {
        const int buf = r & 1;

        // ---- A fragments from LDS (ds_read_b128, conflict-free 16B stride) ----
        short8 af[8];
        #pragma unroll
        for (int j = 0; j < 8; ++j)
            af[j] = __builtin_bit_cast(short8, abuf[buf][j * 64 + lane]);

        // ---- repack current B (split packed hi|lo) from pb ----
        short8 bhi[2], blo[2];
        #pragma unroll
        for (int kh2 = 0; kh2 < 2; ++kh2) {
            union { unsigned d[4]; short8 v; } H, L;
            #pragma unroll
            for (int p = 0; p < 4; ++p) {
                unsigned ua = pb[kh2 * 8 + 2 * p], ub = pb[kh2 * 8 + 2 * p + 1];
                H.d[p] = (ua & 0xffffu) | (ub << 16);
                L.d[p] = (ua >> 16) | (ub & 0xffff0000u);
            }
            bhi[kh2] = H.v;
            blo[kh2] = L.v;
        }

        // ---- issue all 16 MFMAs (independent chains across mt) ----
        f32x4 acc[4];
        #pragma unroll
        for (int mt = 0; mt < 4; ++mt) {
            f32x4 a0 = {0.0f, 0.0f, 0.0f, 0.0f};
            a0 = __builtin_amdgcn_mfma_f32_16x16x32_bf16(af[mt * 2 + 0], bhi[0], a0, 0, 0, 0);
            a0 = __builtin_amdgcn_mfma_f32_16x16x32_bf16(af[mt * 2 + 1], bhi[1], a0, 0, 0, 0);
            a0 = __builtin_amdgcn_mfma_f32_16x16x32_bf16(af[mt * 2 + 0], blo[0], a0, 0, 0, 0);
            a0 = __builtin_amdgcn_mfma_f32_16x16x32_bf16(af[mt * 2 + 1], blo[1], a0, 0, 0, 0);
            acc[mt] = a0;
        }

        // ---- issue next chunk's loads while MFMAs are in flight ----
        uv4 na0, na1;
        if (r < 17) {
            #pragma unroll
            for (int q2 = 0; q2 < 16; ++q2) {
                int k = (r + 1) * 64 + (q2 >> 3) * 32 + quad * 8 + (q2 & 7);
                pb[q2] = xw[ofs_s[k]];
            }
            na0 = awg[(r + 1) * 512 + t];
            na1 = awg[(r + 1) * 512 + t + 256];
        }

        // ---- binarize, count, borderline -> LDS queue ----
        #pragma unroll
        for (int mt = 0; mt < 4; ++mt) {
            #pragma unroll
            for (int i = 0; i < 4; ++i) {
                float s = acc[mt][i];
                int ge = (s >= 0.0f) ? 1 : 0;
                counts[mt][i] += ge;
                if (__builtin_fabsf(s) < TAU) {
                    unsigned idx = atomicAdd(&hitcnt, 1u);   // LDS atomic: fast, rare
                    if (idx < (unsigned)HITCAP) {
                        unsigned m = (unsigned)(g * 64 + mt * 16 + quad * 4 + i);
                        unsigned n = (unsigned)(n0 + wv * 16 + nl);
                        hitbuf[idx] = n | ((unsigned)r << 14) | (m << 19) | ((unsigned)ge << 27);
                    }
                }
            }
        }

        // ---- write next A-slab into the other buffer; one barrier per iter ----
        if (r < 17) {
            abuf[buf ^ 1][t] = na0;
            abuf[buf ^ 1][t + 256] = na1;
        }
        __syncthreads();
    }

    // ---- epilogue: C/D layout col=lane&15 (n), row=quad*4+reg (m) ----
    {
        const int n = n0 + wv * 16 + nl;
        const int p = n & 1023;
        #pragma unroll
        for (int mt = 0; mt < 4; ++mt)
            #pragma unroll
            for (int i = 0; i < 4; ++i) {
                int m = g * 64 + mt * 16 + quad * 4 + i;
                out[(((size_t)(b * 256 + m)) << 10) + p] = (float)counts[mt][i];
            }
    }

    // ---- in-block fixup of this block's own hits (R4 k_fix body, verbatim math) ----
    __syncthreads();
    unsigned tot = hitcnt;
    if (tot > (unsigned)HITCAP) tot = (unsigned)HITCAP;
    for (unsigned i = t; i < tot; i += 256) {
        unsigned u = hitbuf[i];
        int n = u & 16383;
        int r = (u >> 14) & 31;
        int m = (u >> 19) & 255;
        int bit = (u >> 27) & 1;
        int bb = n >> 10, p = n & 1023, y = p >> 5, x = p & 31;
        const float* ib = inp + (size_t)bb * (128 * 32 * 32);
        const float* wp = weight + (size_t)m * 1152;
        float s = 0.0f;
        int d = r * 64;
        for (int c = 0; c < 64; ++c, ++d) {
            int ci = d / 9, rem = d - ci * 9;
            int kh = rem / 3, kw = rem - kh * 3;
            int yy = y + kh - 1, xx = x + kw - 1;
            float xv = 0.0f;
            if ((unsigned)yy < 32u && (unsigned)xx < 32u)
                xv = ib[(ci * 32 + yy) * 32 + xx];
            float q = rintf(__fmul_rn(wp[d], sc));
            q = fminf(fmaxf(q, -7.0f), 7.0f);
            s = __fadd_rn(s, __fmul_rn(xv, q));
        }
        int nb = (s >= 0.0f) ? 1 : 0;
        if (nb != bit)
            atomicAdd(&out[(((size_t)(bb * 256 + m)) << 10) + p], nb ? 1.0f : -1.0f);
    }
}

extern "C" void kernel_launch(void* const* d_in, const int* in_sizes, int n_in,
                              void* d_out, int out_size, void* d_ws, size_t ws_size,
                              hipStream_t stream) {
    const float* inp    = (const float*)d_in[0];   // [16,128,32,32]
    const float* weight = (const float*)d_in[1];   // [256,128,3,3]
    float* out = (float*)d_out;                    // [16,256,32,32]

    char* ws = (char*)d_ws;
    float*    scale = (float*)(ws + 0);
    uv4*      wqb   = (uv4*)(ws + 1024);          // 589,824 B
    unsigned* xpk   = (unsigned*)(ws + 590848);   // 9,469,952 B

    k_prep<<<2192, 256, 0, stream>>>(weight, inp, scale, xpk, wqb);

    dim3 grid(256, 4);   // (N/64, M/64) -> 1024 blocks
    k_main<<<grid, 256, 0, stream>>>(xpk, wqb, inp, weight, scale, out);
}